// Round 14
// baseline (264.594 us; speedup 1.0000x reference)
//
#include <hip/hip_runtime.h>
#include <hip/hip_fp16.h>

#define NEG_SLOPE 0.2f
#define GAT_EPS 1e-16f
#define CHUNK_LOG 14
#define CHUNK (1 << CHUNK_LOG)   // edges per histogram block
#define NWMAX 25088              // LDS u32 words (>= N/2 = 25000)

// ---- prep: w2as = W2 @ a_src2, w2ad = W2 @ a_dst2 (W2 is [64,128] row-major) ----
__global__ __launch_bounds__(128) void prep_kernel(
    const float* __restrict__ W2, const float* __restrict__ a_s2,
    const float* __restrict__ a_d2, float* __restrict__ w2as,
    float* __restrict__ w2ad) {
  const int t = threadIdx.x;  // 128 threads
  const int c = t & 63;
  const float* av = (t < 64) ? a_s2 : a_d2;
  float s = 0.f;
  for (int j = 0; j < 128; ++j) s = fmaf(W2[c * 128 + j], av[j], s);
  if (t < 64) w2as[c] = s; else w2ad[c] = s;
}

// ---- GEMM1: h1 = x @ W1 (128 -> 64) as fp16 + alpha reductions ----
__global__ __launch_bounds__(256) void gemm1_kernel(
    const float* __restrict__ x, const float* __restrict__ W1,
    const float* __restrict__ a_src, const float* __restrict__ a_dst,
    __half* __restrict__ h16, float* __restrict__ as_out,
    float* __restrict__ ad_out, int N) {
  __shared__ float Wl[128 * 64];      // 32 KB, loaded once
  __shared__ float xsh[4][4][128];    // 8 KB: per-wave staging (wave, row, k)
  const int t = threadIdx.x;
  {
    const float4* Wv = (const float4*)W1;
    float4* Wd = (float4*)Wl;
    for (int i = t; i < 128 * 64 / 4; i += 256) Wd[i] = Wv[i];
  }
  __syncthreads();
  const int lane = t & 63;
  const int wave = t >> 6;
  const int wid = blockIdx.x * 4 + wave;
  const int nwaves = gridDim.x * 4;
  const float asl = a_src[lane], adl = a_dst[lane];
  for (int row4 = wid * 4; row4 < N; row4 += nwaves * 4) {
    const int r0 = row4;
    const int r1 = min(row4 + 1, N - 1);
    const int r2 = min(row4 + 2, N - 1);
    const int r3 = min(row4 + 3, N - 1);
    float2 v0 = *(const float2*)(x + (size_t)r0 * 128 + lane * 2);
    float2 v1 = *(const float2*)(x + (size_t)r1 * 128 + lane * 2);
    float2 v2 = *(const float2*)(x + (size_t)r2 * 128 + lane * 2);
    float2 v3 = *(const float2*)(x + (size_t)r3 * 128 + lane * 2);
    *(float2*)&xsh[wave][0][lane * 2] = v0;
    *(float2*)&xsh[wave][1][lane * 2] = v1;
    *(float2*)&xsh[wave][2][lane * 2] = v2;
    *(float2*)&xsh[wave][3][lane * 2] = v3;
    float a0 = 0.f, a1 = 0.f, a2 = 0.f, a3 = 0.f;
#pragma unroll 4
    for (int kq = 0; kq < 128; kq += 4) {
      float4 x0 = *(const float4*)&xsh[wave][0][kq];  // uniform -> broadcast
      float4 x1 = *(const float4*)&xsh[wave][1][kq];
      float4 x2 = *(const float4*)&xsh[wave][2][kq];
      float4 x3 = *(const float4*)&xsh[wave][3][kq];
      float w0 = Wl[(kq + 0) * 64 + lane];
      float w1 = Wl[(kq + 1) * 64 + lane];
      float w2 = Wl[(kq + 2) * 64 + lane];
      float w3 = Wl[(kq + 3) * 64 + lane];
      a0 = fmaf(x0.x, w0, a0); a0 = fmaf(x0.y, w1, a0);
      a0 = fmaf(x0.z, w2, a0); a0 = fmaf(x0.w, w3, a0);
      a1 = fmaf(x1.x, w0, a1); a1 = fmaf(x1.y, w1, a1);
      a1 = fmaf(x1.z, w2, a1); a1 = fmaf(x1.w, w3, a1);
      a2 = fmaf(x2.x, w0, a2); a2 = fmaf(x2.y, w1, a2);
      a2 = fmaf(x2.z, w2, a2); a2 = fmaf(x2.w, w3, a2);
      a3 = fmaf(x3.x, w0, a3); a3 = fmaf(x3.y, w1, a3);
      a3 = fmaf(x3.z, w2, a3); a3 = fmaf(x3.w, w3, a3);
    }
    float acc[4] = {a0, a1, a2, a3};
#pragma unroll
    for (int r = 0; r < 4; ++r) {
      const int row = row4 + r;
      if (row >= N) break;
      h16[(size_t)row * 64 + lane] = __float2half(acc[r]);
      float va = acc[r] * asl;
      float vd = acc[r] * adl;
#pragma unroll
      for (int off = 32; off > 0; off >>= 1) {
        va += __shfl_down(va, off, 64);
        vd += __shfl_down(vd, off, 64);
      }
      if (lane == 0) { as_out[row] = va; ad_out[row] = vd; }
    }
  }
}

// ---- Pass A: per-block LDS histogram (u16 pairs) + local rank, no global atomics ----
__global__ __launch_bounds__(256) void hist_local_kernel(
    const int* __restrict__ dsts, int E, int ET,
    unsigned* __restrict__ hist_g, unsigned short* __restrict__ rank) {
  __shared__ unsigned h[NWMAX];  // ~100 KB: N/2 packed u16 counter pairs
  const int t = threadIdx.x;
  for (int w = t; w < NWMAX; w += 256) h[w] = 0u;
  __syncthreads();
  const int b = blockIdx.x;
  const int beg = b << CHUNK_LOG;
  const int end = min(beg + CHUNK, ET);
  for (int i = beg + t; i < end; i += 256) {
    int d = (i < E) ? dsts[i] : i - E;
    unsigned sh = (unsigned)(d & 1) * 16u;
    unsigned old = atomicAdd(&h[d >> 1], 1u << sh);
    rank[i] = (unsigned short)((old >> sh) & 0xffffu);
  }
  __syncthreads();
  unsigned* hg = hist_g + (size_t)b * (NWMAX);
  for (int w = t; w < NWMAX; w += 256) hg[w] = h[w];
}

// ---- Pass B: per-node exclusive prefix over blocks (in place) + totals ----
__global__ __launch_bounds__(256) void col_scan_kernel(
    unsigned* __restrict__ hist_g, int* __restrict__ count, int NW, int HB) {
  const int w = blockIdx.x * 256 + threadIdx.x;
  if (w >= NW) return;
  unsigned s0 = 0, s1 = 0;
#pragma unroll 4
  for (int b = 0; b < HB; ++b) {
    unsigned* p = hist_g + (size_t)b * (NWMAX) + w;
    unsigned v = *p;
    *p = s0 | (s1 << 16);
    s0 += v & 0xffffu;
    s1 += v >> 16;
  }
  ((int2*)count)[w] = make_int2((int)s0, (int)s1);
}

// ---- single-kernel exclusive scan: count[N] -> row_ptr[N+1] ----
__global__ __launch_bounds__(1024) void scan_one_kernel(
    const int* __restrict__ count, int* __restrict__ row_ptr, int N, int ET) {
  __shared__ int part[1024];
  const int t = threadIdx.x;
  const int C = (N + 1023) / 1024;
  const int beg = t * C, end = min(beg + C, N);
  int s = 0;
  for (int i = beg; i < end; ++i) s += count[i];
  part[t] = s;
  __syncthreads();
  for (int off = 1; off < 1024; off <<= 1) {
    int add = (t >= off) ? part[t - off] : 0;
    __syncthreads();
    part[t] += add;
    __syncthreads();
  }
  int ex = part[t] - s;  // exclusive prefix of this thread's range
  for (int i = beg; i < end; ++i) {
    int v = count[i];
    row_ptr[i] = ex;
    ex += v;
  }
  if (t == 1023) row_ptr[N] = ET;
}

// ---- Pass C: atomic-free scatter, 4-edge packs (8 gathers in flight) ----
__global__ __launch_bounds__(256) void scatter2_kernel(
    const int* __restrict__ srcs, const int* __restrict__ dsts,
    const int* __restrict__ row_ptr, const unsigned* __restrict__ hist_g,
    const unsigned short* __restrict__ rank, int E, int ET,
    int* __restrict__ ssrc) {
  const int np = ET >> 2;
  for (int p = blockIdx.x * blockDim.x + threadIdx.x; p < np;
       p += gridDim.x * blockDim.x) {
    const int base = p * 4;
    int4 s4, d4;
    if (base + 3 < E) {
      s4 = *(const int4*)(srcs + base);
      d4 = *(const int4*)(dsts + base);
    } else {
      s4.x = d4.x = base + 0 - E;
      s4.y = d4.y = base + 1 - E;
      s4.z = d4.z = base + 2 - E;
      s4.w = d4.w = base + 3 - E;
      if (base + 0 < E) { s4.x = srcs[base + 0]; d4.x = dsts[base + 0]; }
      if (base + 1 < E) { s4.y = srcs[base + 1]; d4.y = dsts[base + 1]; }
      if (base + 2 < E) { s4.z = srcs[base + 2]; d4.z = dsts[base + 2]; }
      if (base + 3 < E) { s4.w = srcs[base + 3]; d4.w = dsts[base + 3]; }
    }
    ushort4 r4 = *(const ushort4*)(rank + base);
    // 4-pack never straddles a chunk boundary (CHUNK % 4 == 0)
    const unsigned* hg = hist_g + ((size_t)(base >> CHUNK_LOG)) * (NWMAX);
    // 4 independent gather chains
    int rp0 = row_ptr[d4.x], rp1 = row_ptr[d4.y];
    int rp2 = row_ptr[d4.z], rp3 = row_ptr[d4.w];
    unsigned h0 = hg[d4.x >> 1], h1 = hg[d4.y >> 1];
    unsigned h2 = hg[d4.z >> 1], h3 = hg[d4.w >> 1];
    int o0 = (int)((h0 >> ((unsigned)(d4.x & 1) * 16u)) & 0xffffu);
    int o1 = (int)((h1 >> ((unsigned)(d4.y & 1) * 16u)) & 0xffffu);
    int o2 = (int)((h2 >> ((unsigned)(d4.z & 1) * 16u)) & 0xffffu);
    int o3 = (int)((h3 >> ((unsigned)(d4.w & 1) * 16u)) & 0xffffu);
    ssrc[rp0 + o0 + (int)r4.x] = s4.x;
    ssrc[rp1 + o1 + (int)r4.y] = s4.y;
    ssrc[rp2 + o2 + (int)r4.z] = s4.z;
    ssrc[rp3 + o3 + (int)r4.w] = s4.w;
  }
  // scalar tail (ET % 4)
  if (blockIdx.x == 0 && threadIdx.x < (ET & 3)) {
    int i = (np << 2) + threadIdx.x;
    int s = (i < E) ? srcs[i] : i - E;
    int d = (i < E) ? dsts[i] : i - E;
    const unsigned* hg = hist_g + ((size_t)(i >> CHUNK_LOG)) * (NWMAX);
    int off = (int)((hg[d >> 1] >> ((unsigned)(d & 1) * 16u)) & 0xffffu);
    ssrc[row_ptr[d] + off + (int)rank[i]] = s;
  }
}

// ---- fused per-node aggregation: one wave/node, phase-split attention via
// per-wave LDS staging (no-barrier same-wave idiom). ----
template <int LAYER>
__global__ __launch_bounds__(256) void node_agg_kernel(
    const int* __restrict__ row_ptr, const int* __restrict__ ssrc,
    const float* __restrict__ as, const float* __restrict__ ad_arr,
    const __half* __restrict__ hsrc, const float* __restrict__ b1,
    const float* __restrict__ w2as, const float* __restrict__ w2ad,
    __half* __restrict__ rl1, float* __restrict__ as2,
    float* __restrict__ ad2, float* __restrict__ agg2, int N) {
  __shared__ int   s_s[4][64];   // per-wave staged src ids
  __shared__ float s_p[4][64];   // per-wave staged edge weights
  const int lane = threadIdx.x & 63;
  const int wave = threadIdx.x >> 6;
  const int half = lane >> 5;       // 0: even edges, 1: odd edges
  const int hl = lane & 31;         // feature pair index
  const int node = blockIdx.x * 4 + wave;
  if (node >= N) return;
  const int beg = row_ptr[node], end = row_ptr[node + 1];
  const float ad = ad_arr[node];

  float acc0A = 0.f, acc1A = 0.f, acc0B = 0.f, acc1B = 0.f;
  float SlL = 0.f;  // per-lane exp-sum (phase 1)
  for (int tb = beg; tb < end; tb += 64) {
    const int nt = min(64, end - tb);
    // ---- phase 1: lane-parallel attention (once per edge), stage to LDS ----
    if (lane < nt) {
      int s = ssrc[tb + lane];          // coalesced
      float e = as[s] + ad;
      e = e > 0.f ? e : NEG_SLOPE * e;
      float pe = __expf(e);
      SlL += pe;
      s_s[wave][lane] = s;
      s_p[wave][lane] = pe;
    }
    // same-wave ds_write -> ds_read: in-order LDS, no barrier needed
    // ---- phase 2: feature accumulation, half-wave split ----
    int k = half;
    for (; k + 6 < nt; k += 8) {
      int s0 = s_s[wave][k];
      int s1 = s_s[wave][k + 2];
      int s2 = s_s[wave][k + 4];
      int s3 = s_s[wave][k + 6];
      float p0 = s_p[wave][k];
      float p1 = s_p[wave][k + 2];
      float p2 = s_p[wave][k + 4];
      float p3 = s_p[wave][k + 6];
      float2 f0 = __half22float2(*(const __half2*)(hsrc + (size_t)s0 * 64 + 2 * hl));
      float2 f1 = __half22float2(*(const __half2*)(hsrc + (size_t)s1 * 64 + 2 * hl));
      float2 f2 = __half22float2(*(const __half2*)(hsrc + (size_t)s2 * 64 + 2 * hl));
      float2 f3 = __half22float2(*(const __half2*)(hsrc + (size_t)s3 * 64 + 2 * hl));
      acc0A = fmaf(p0, f0.x, acc0A); acc1A = fmaf(p0, f0.y, acc1A);
      acc0B = fmaf(p1, f1.x, acc0B); acc1B = fmaf(p1, f1.y, acc1B);
      acc0A = fmaf(p2, f2.x, acc0A); acc1A = fmaf(p2, f2.y, acc1A);
      acc0B = fmaf(p3, f3.x, acc0B); acc1B = fmaf(p3, f3.y, acc1B);
    }
    for (; k < nt; k += 2) {
      int s0 = s_s[wave][k];
      float p0 = s_p[wave][k];
      float2 f0 = __half22float2(*(const __half2*)(hsrc + (size_t)s0 * 64 + 2 * hl));
      acc0A = fmaf(p0, f0.x, acc0A); acc1A = fmaf(p0, f0.y, acc1A);
    }
  }
  float acc0 = acc0A + acc0B, acc1 = acc1A + acc1B;
  acc0 += __shfl_xor(acc0, 32, 64);
  acc1 += __shfl_xor(acc1, 32, 64);
  float Sl = SlL;
#pragma unroll
  for (int off = 32; off > 0; off >>= 1) Sl += __shfl_xor(Sl, off, 64);
  const float inv = 1.f / (Sl + GAT_EPS);

  if (LAYER == 1) {
    float2 bb = ((const float2*)b1)[hl];
    float r0 = fmaxf(fmaf(acc0, inv, bb.x), 0.f);
    float r1 = fmaxf(fmaf(acc1, inv, bb.y), 0.f);
    if (half == 0)
      *(__half2*)(rl1 + (size_t)node * 64 + 2 * hl) = __floats2half2_rn(r0, r1);
    float2 was = ((const float2*)w2as)[hl];
    float2 wad = ((const float2*)w2ad)[hl];
    float va = fmaf(r0, was.x, r1 * was.y);
    float vd = fmaf(r0, wad.x, r1 * wad.y);
#pragma unroll
    for (int off = 16; off > 0; off >>= 1) {
      va += __shfl_xor(va, off, 64);
      vd += __shfl_xor(vd, off, 64);
    }
    if (lane == 0) { as2[node] = va; ad2[node] = vd; }
  } else {
    if (half == 0) {
      float2 o; o.x = acc0 * inv; o.y = acc1 * inv;
      *(float2*)(agg2 + (size_t)node * 64 + 2 * hl) = o;
    }
  }
}

// ---- final GEMM: out = agg2 @ W2 + b2 (64 -> 128) ----
__global__ __launch_bounds__(256) void gemm_out_kernel(
    const float* __restrict__ agg2, const float* __restrict__ W2,
    const float* __restrict__ b2, float* __restrict__ out, int N) {
  __shared__ float Wl[64 * 128];    // 32 KB, loaded once
  __shared__ float xsh[4][4][64];   // 4 KB: per-wave staging
  const int t = threadIdx.x;
  {
    const float4* Wv = (const float4*)W2;
    float4* Wd = (float4*)Wl;
    for (int i = t; i < 64 * 128 / 4; i += 256) Wd[i] = Wv[i];
  }
  __syncthreads();
  const int lane = t & 63;
  const int wave = t >> 6;
  const int wid = blockIdx.x * 4 + wave;
  const int npairs = gridDim.x * 2;          // wave pairs
  const int pair = wid >> 1;
  const int col = (wid & 1) * 64 + lane;     // 0..127
  const float bc = b2[col];
  for (int row4 = pair * 4; row4 < N; row4 += npairs * 4) {
    const int r0 = row4;
    const int r1 = min(row4 + 1, N - 1);
    const int r2 = min(row4 + 2, N - 1);
    const int r3 = min(row4 + 3, N - 1);
    xsh[wave][0][lane] = agg2[(size_t)r0 * 64 + lane];
    xsh[wave][1][lane] = agg2[(size_t)r1 * 64 + lane];
    xsh[wave][2][lane] = agg2[(size_t)r2 * 64 + lane];
    xsh[wave][3][lane] = agg2[(size_t)r3 * 64 + lane];
    float a0 = bc, a1 = bc, a2 = bc, a3 = bc;
#pragma unroll 4
    for (int kq = 0; kq < 64; kq += 4) {
      float4 x0 = *(const float4*)&xsh[wave][0][kq];  // uniform -> broadcast
      float4 x1 = *(const float4*)&xsh[wave][1][kq];
      float4 x2 = *(const float4*)&xsh[wave][2][kq];
      float4 x3 = *(const float4*)&xsh[wave][3][kq];
      float w0 = Wl[(kq + 0) * 128 + col];
      float w1 = Wl[(kq + 1) * 128 + col];
      float w2 = Wl[(kq + 2) * 128 + col];
      float w3 = Wl[(kq + 3) * 128 + col];
      a0 = fmaf(x0.x, w0, a0); a0 = fmaf(x0.y, w1, a0);
      a0 = fmaf(x0.z, w2, a0); a0 = fmaf(x0.w, w3, a0);
      a1 = fmaf(x1.x, w0, a1); a1 = fmaf(x1.y, w1, a1);
      a1 = fmaf(x1.z, w2, a1); a1 = fmaf(x1.w, w3, a1);
      a2 = fmaf(x2.x, w0, a2); a2 = fmaf(x2.y, w1, a2);
      a2 = fmaf(x2.z, w2, a2); a2 = fmaf(x2.w, w3, a2);
      a3 = fmaf(x3.x, w0, a3); a3 = fmaf(x3.y, w1, a3);
      a3 = fmaf(x3.z, w2, a3); a3 = fmaf(x3.w, w3, a3);
    }
    if (r0 < N) out[(size_t)r0 * 128 + col] = a0;
    if (row4 + 1 < N) out[(size_t)r1 * 128 + col] = a1;
    if (row4 + 2 < N) out[(size_t)r2 * 128 + col] = a2;
    if (row4 + 3 < N) out[(size_t)r3 * 128 + col] = a3;
  }
}

extern "C" void kernel_launch(void* const* d_in, const int* in_sizes, int n_in,
                              void* d_out, int out_size, void* d_ws, size_t ws_size,
                              hipStream_t stream) {
  const float* x    = (const float*)d_in[0];
  const int*   ei   = (const int*)d_in[1];
  const float* W1   = (const float*)d_in[2];
  const float* a_s1 = (const float*)d_in[3];
  const float* a_d1 = (const float*)d_in[4];
  const float* b1   = (const float*)d_in[5];
  const float* W2   = (const float*)d_in[6];
  const float* a_s2 = (const float*)d_in[7];
  const float* a_d2 = (const float*)d_in[8];
  const float* b2   = (const float*)d_in[9];

  const int N  = in_sizes[0] / 128;   // 50000
  const int E  = in_sizes[1] / 2;     // 1200000
  const int ET = E + N;               // 1250000
  const int* srcs = ei;
  const int* dsts = ei + E;
  const int NW = N / 2;                           // 25000 packed counter words
  const int HB = (ET + CHUNK - 1) >> CHUNK_LOG;   // 77 histogram blocks

  // workspace layout
  char* w = (char*)d_ws;
  __half* h16  = (__half*)w;            w += (size_t)N * 64 * 2;
  __half* rl1  = (__half*)w;            w += (size_t)N * 64 * 2;
  float* agg2  = (float*)w;             w += (size_t)N * 64 * 4;  // 12.8 MB
  float* as1   = (float*)w;             w += (size_t)N * 4;
  float* ad1   = (float*)w;             w += (size_t)N * 4;
  float* as2   = (float*)w;             w += (size_t)N * 4;
  float* ad2   = (float*)w;             w += (size_t)N * 4;
  float* w2as  = (float*)w;             w += 64 * 4;
  float* w2ad  = (float*)w;             w += 64 * 4;
  int* row_ptr = (int*)w;               w += (size_t)(N + 1) * 4;
  int* count   = (int*)w;               w += (size_t)N * 4;
  unsigned short* rank = (unsigned short*)w;  w += (size_t)ET * 2;
  int* ssrc    = (int*)w;               w += (size_t)ET * 4;
  // hist_g aliases agg2: lifetimes disjoint (CSR build vs layer-2 output).
  unsigned* hist_g = (unsigned*)agg2;

  float* out = (float*)d_out;  // N*128

  // ---- build CSR + sorted src permutation (zero global atomics) ----
  hist_local_kernel<<<HB, 256, 0, stream>>>(dsts, E, ET, hist_g, rank);
  col_scan_kernel<<<(NW + 255) / 256, 256, 0, stream>>>(hist_g, count, NW, HB);
  scan_one_kernel<<<1, 1024, 0, stream>>>(count, row_ptr, N, ET);
  scatter2_kernel<<<2048, 256, 0, stream>>>(srcs, dsts, row_ptr, hist_g, rank,
                                            E, ET, ssrc);

  // ---- weights prep + layer-1 features ----
  prep_kernel<<<1, 128, 0, stream>>>(W2, a_s2, a_d2, w2as, w2ad);
  gemm1_kernel<<<1024, 256, 0, stream>>>(x, W1, a_s1, a_d1, h16, as1, ad1, N);
  // ---- layer-1 aggregation (phase-split attention, LDS staging) ----
  node_agg_kernel<1><<<(N + 3) / 4, 256, 0, stream>>>(
      row_ptr, ssrc, as1, ad1, h16, b1, w2as, w2ad, rl1, as2, ad2,
      (float*)nullptr, N);
  // ---- layer-2 aggregation (64-dim, W2 commuted out) ----
  node_agg_kernel<2><<<(N + 3) / 4, 256, 0, stream>>>(
      row_ptr, ssrc, as2, ad2, rl1, b1, w2as, w2ad, ((__half*)nullptr),
      (float*)nullptr, (float*)nullptr, agg2, N);
  // ---- final GEMM ----
  gemm_out_kernel<<<1024, 256, 0, stream>>>(agg2, W2, b2, out, N);
}

// Round 15
// 196.780 us; speedup vs baseline: 1.3446x; 1.3446x over previous
//
#include <hip/hip_runtime.h>
#include <hip/hip_fp16.h>

#define NEG_SLOPE 0.2f
#define GAT_EPS 1e-16f
#define CHUNK_LOG 14
#define CHUNK (1 << CHUNK_LOG)   // edges per histogram block
#define NWMAX 25088              // LDS u32 words (>= N/2 = 25000)

// ---- prep: w2as = W2 @ a_src2, w2ad = W2 @ a_dst2 (W2 is [64,128] row-major) ----
__global__ __launch_bounds__(128) void prep_kernel(
    const float* __restrict__ W2, const float* __restrict__ a_s2,
    const float* __restrict__ a_d2, float* __restrict__ w2as,
    float* __restrict__ w2ad) {
  const int t = threadIdx.x;  // 128 threads
  const int c = t & 63;
  const float* av = (t < 64) ? a_s2 : a_d2;
  float s = 0.f;
  for (int j = 0; j < 128; ++j) s = fmaf(W2[c * 128 + j], av[j], s);
  if (t < 64) w2as[c] = s; else w2ad[c] = s;
}

// ---- GEMM1: h1 = x @ W1 (128 -> 64) as fp16 + alpha reductions ----
__global__ __launch_bounds__(256) void gemm1_kernel(
    const float* __restrict__ x, const float* __restrict__ W1,
    const float* __restrict__ a_src, const float* __restrict__ a_dst,
    __half* __restrict__ h16, float* __restrict__ as_out,
    float* __restrict__ ad_out, int N) {
  __shared__ float Wl[128 * 64];      // 32 KB, loaded once
  __shared__ float xsh[4][4][128];    // 8 KB: per-wave staging (wave, row, k)
  const int t = threadIdx.x;
  {
    const float4* Wv = (const float4*)W1;
    float4* Wd = (float4*)Wl;
    for (int i = t; i < 128 * 64 / 4; i += 256) Wd[i] = Wv[i];
  }
  __syncthreads();
  const int lane = t & 63;
  const int wave = t >> 6;
  const int wid = blockIdx.x * 4 + wave;
  const int nwaves = gridDim.x * 4;
  const float asl = a_src[lane], adl = a_dst[lane];
  for (int row4 = wid * 4; row4 < N; row4 += nwaves * 4) {
    const int r0 = row4;
    const int r1 = min(row4 + 1, N - 1);
    const int r2 = min(row4 + 2, N - 1);
    const int r3 = min(row4 + 3, N - 1);
    float2 v0 = *(const float2*)(x + (size_t)r0 * 128 + lane * 2);
    float2 v1 = *(const float2*)(x + (size_t)r1 * 128 + lane * 2);
    float2 v2 = *(const float2*)(x + (size_t)r2 * 128 + lane * 2);
    float2 v3 = *(const float2*)(x + (size_t)r3 * 128 + lane * 2);
    *(float2*)&xsh[wave][0][lane * 2] = v0;
    *(float2*)&xsh[wave][1][lane * 2] = v1;
    *(float2*)&xsh[wave][2][lane * 2] = v2;
    *(float2*)&xsh[wave][3][lane * 2] = v3;
    float a0 = 0.f, a1 = 0.f, a2 = 0.f, a3 = 0.f;
#pragma unroll 4
    for (int kq = 0; kq < 128; kq += 4) {
      float4 x0 = *(const float4*)&xsh[wave][0][kq];  // uniform -> broadcast
      float4 x1 = *(const float4*)&xsh[wave][1][kq];
      float4 x2 = *(const float4*)&xsh[wave][2][kq];
      float4 x3 = *(const float4*)&xsh[wave][3][kq];
      float w0 = Wl[(kq + 0) * 64 + lane];
      float w1 = Wl[(kq + 1) * 64 + lane];
      float w2 = Wl[(kq + 2) * 64 + lane];
      float w3 = Wl[(kq + 3) * 64 + lane];
      a0 = fmaf(x0.x, w0, a0); a0 = fmaf(x0.y, w1, a0);
      a0 = fmaf(x0.z, w2, a0); a0 = fmaf(x0.w, w3, a0);
      a1 = fmaf(x1.x, w0, a1); a1 = fmaf(x1.y, w1, a1);
      a1 = fmaf(x1.z, w2, a1); a1 = fmaf(x1.w, w3, a1);
      a2 = fmaf(x2.x, w0, a2); a2 = fmaf(x2.y, w1, a2);
      a2 = fmaf(x2.z, w2, a2); a2 = fmaf(x2.w, w3, a2);
      a3 = fmaf(x3.x, w0, a3); a3 = fmaf(x3.y, w1, a3);
      a3 = fmaf(x3.z, w2, a3); a3 = fmaf(x3.w, w3, a3);
    }
    float acc[4] = {a0, a1, a2, a3};
#pragma unroll
    for (int r = 0; r < 4; ++r) {
      const int row = row4 + r;
      if (row >= N) break;
      h16[(size_t)row * 64 + lane] = __float2half(acc[r]);
      float va = acc[r] * asl;
      float vd = acc[r] * adl;
#pragma unroll
      for (int off = 32; off > 0; off >>= 1) {
        va += __shfl_down(va, off, 64);
        vd += __shfl_down(vd, off, 64);
      }
      if (lane == 0) { as_out[row] = va; ad_out[row] = vd; }
    }
  }
}

// ---- Pass A: per-block LDS histogram (u16 pairs) + local rank, no global atomics ----
__global__ __launch_bounds__(256) void hist_local_kernel(
    const int* __restrict__ dsts, int E, int ET,
    unsigned* __restrict__ hist_g, unsigned short* __restrict__ rank) {
  __shared__ unsigned h[NWMAX];  // ~100 KB: N/2 packed u16 counter pairs
  const int t = threadIdx.x;
  for (int w = t; w < NWMAX; w += 256) h[w] = 0u;
  __syncthreads();
  const int b = blockIdx.x;
  const int beg = b << CHUNK_LOG;
  const int end = min(beg + CHUNK, ET);
  for (int i = beg + t; i < end; i += 256) {
    int d = (i < E) ? dsts[i] : i - E;
    unsigned sh = (unsigned)(d & 1) * 16u;
    unsigned old = atomicAdd(&h[d >> 1], 1u << sh);
    rank[i] = (unsigned short)((old >> sh) & 0xffffu);
  }
  __syncthreads();
  unsigned* hg = hist_g + (size_t)b * (NWMAX);
  for (int w = t; w < NWMAX; w += 256) hg[w] = h[w];
}

// ---- Pass B: per-node exclusive prefix over blocks (in place) + totals ----
__global__ __launch_bounds__(256) void col_scan_kernel(
    unsigned* __restrict__ hist_g, int* __restrict__ count, int NW, int HB) {
  const int w = blockIdx.x * 256 + threadIdx.x;
  if (w >= NW) return;
  unsigned s0 = 0, s1 = 0;
#pragma unroll 4
  for (int b = 0; b < HB; ++b) {
    unsigned* p = hist_g + (size_t)b * (NWMAX) + w;
    unsigned v = *p;
    *p = s0 | (s1 << 16);
    s0 += v & 0xffffu;
    s1 += v >> 16;
  }
  ((int2*)count)[w] = make_int2((int)s0, (int)s1);
}

// ---- 3-stage exclusive scan over count[N] -> row_ptr[N+1] ----
__global__ __launch_bounds__(256) void scan_blocks_kernel(
    const int* __restrict__ count, int* __restrict__ row_ptr,
    int* __restrict__ bsums, int N) {
  __shared__ int sd[256];
  const int t = threadIdx.x;
  const int i = blockIdx.x * 256 + t;
  int v = (i < N) ? count[i] : 0;
  sd[t] = v;
  __syncthreads();
  for (int off = 1; off < 256; off <<= 1) {
    int add = (t >= off) ? sd[t - off] : 0;
    __syncthreads();
    sd[t] += add;
    __syncthreads();
  }
  if (i < N) row_ptr[i] = sd[t] - v;  // exclusive, partial
  if (t == 255) bsums[blockIdx.x] = sd[255];
}

__global__ __launch_bounds__(256) void scan_top_kernel(int* __restrict__ bsums,
                                                       int nblk) {
  __shared__ int sd[256];
  const int t = threadIdx.x;
  int v = (t < nblk) ? bsums[t] : 0;
  sd[t] = v;
  __syncthreads();
  for (int off = 1; off < 256; off <<= 1) {
    int add = (t >= off) ? sd[t - off] : 0;
    __syncthreads();
    sd[t] += add;
    __syncthreads();
  }
  if (t < nblk) bsums[t] = sd[t] - v;  // exclusive
}

__global__ __launch_bounds__(256) void scan_add_kernel(
    int* __restrict__ row_ptr, const int* __restrict__ bsums, int N, int ET) {
  const int i = blockIdx.x * 256 + threadIdx.x;
  if (i < N) row_ptr[i] += bsums[blockIdx.x];
  if (i == 0) row_ptr[N] = ET;
}

// ---- Pass C: atomic-free scatter, 4-edge packs (8 gathers in flight) ----
__global__ __launch_bounds__(256) void scatter2_kernel(
    const int* __restrict__ srcs, const int* __restrict__ dsts,
    const int* __restrict__ row_ptr, const unsigned* __restrict__ hist_g,
    const unsigned short* __restrict__ rank, int E, int ET,
    int* __restrict__ ssrc) {
  const int np = ET >> 2;
  for (int p = blockIdx.x * blockDim.x + threadIdx.x; p < np;
       p += gridDim.x * blockDim.x) {
    const int base = p * 4;
    int4 s4, d4;
    if (base + 3 < E) {
      s4 = *(const int4*)(srcs + base);
      d4 = *(const int4*)(dsts + base);
    } else {
      s4.x = d4.x = base + 0 - E;
      s4.y = d4.y = base + 1 - E;
      s4.z = d4.z = base + 2 - E;
      s4.w = d4.w = base + 3 - E;
      if (base + 0 < E) { s4.x = srcs[base + 0]; d4.x = dsts[base + 0]; }
      if (base + 1 < E) { s4.y = srcs[base + 1]; d4.y = dsts[base + 1]; }
      if (base + 2 < E) { s4.z = srcs[base + 2]; d4.z = dsts[base + 2]; }
      if (base + 3 < E) { s4.w = srcs[base + 3]; d4.w = dsts[base + 3]; }
    }
    ushort4 r4 = *(const ushort4*)(rank + base);
    // 4-pack never straddles a chunk boundary (CHUNK % 4 == 0)
    const unsigned* hg = hist_g + ((size_t)(base >> CHUNK_LOG)) * (NWMAX);
    int rp0 = row_ptr[d4.x], rp1 = row_ptr[d4.y];
    int rp2 = row_ptr[d4.z], rp3 = row_ptr[d4.w];
    unsigned h0 = hg[d4.x >> 1], h1 = hg[d4.y >> 1];
    unsigned h2 = hg[d4.z >> 1], h3 = hg[d4.w >> 1];
    int o0 = (int)((h0 >> ((unsigned)(d4.x & 1) * 16u)) & 0xffffu);
    int o1 = (int)((h1 >> ((unsigned)(d4.y & 1) * 16u)) & 0xffffu);
    int o2 = (int)((h2 >> ((unsigned)(d4.z & 1) * 16u)) & 0xffffu);
    int o3 = (int)((h3 >> ((unsigned)(d4.w & 1) * 16u)) & 0xffffu);
    ssrc[rp0 + o0 + (int)r4.x] = s4.x;
    ssrc[rp1 + o1 + (int)r4.y] = s4.y;
    ssrc[rp2 + o2 + (int)r4.z] = s4.z;
    ssrc[rp3 + o3 + (int)r4.w] = s4.w;
  }
  // scalar tail (ET % 4)
  if (blockIdx.x == 0 && threadIdx.x < (ET & 3)) {
    int i = (np << 2) + threadIdx.x;
    int s = (i < E) ? srcs[i] : i - E;
    int d = (i < E) ? dsts[i] : i - E;
    const unsigned* hg = hist_g + ((size_t)(i >> CHUNK_LOG)) * (NWMAX);
    int off = (int)((hg[d >> 1] >> ((unsigned)(d & 1) * 16u)) & 0xffffu);
    ssrc[row_ptr[d] + off + (int)rank[i]] = s;
  }
}

// ---- fused per-node aggregation: one wave/node, phase-split attention via
// per-wave LDS staging (no-barrier same-wave idiom). ----
template <int LAYER>
__global__ __launch_bounds__(256) void node_agg_kernel(
    const int* __restrict__ row_ptr, const int* __restrict__ ssrc,
    const float* __restrict__ as, const float* __restrict__ ad_arr,
    const __half* __restrict__ hsrc, const float* __restrict__ b1,
    const float* __restrict__ w2as, const float* __restrict__ w2ad,
    __half* __restrict__ rl1, float* __restrict__ as2,
    float* __restrict__ ad2, float* __restrict__ agg2, int N) {
  __shared__ int   s_s[4][64];   // per-wave staged src ids
  __shared__ float s_p[4][64];   // per-wave staged edge weights
  const int lane = threadIdx.x & 63;
  const int wave = threadIdx.x >> 6;
  const int half = lane >> 5;       // 0: even edges, 1: odd edges
  const int hl = lane & 31;         // feature pair index
  const int node = blockIdx.x * 4 + wave;
  if (node >= N) return;
  const int beg = row_ptr[node], end = row_ptr[node + 1];
  const float ad = ad_arr[node];

  float acc0A = 0.f, acc1A = 0.f, acc0B = 0.f, acc1B = 0.f;
  float SlL = 0.f;  // per-lane exp-sum (phase 1)
  for (int tb = beg; tb < end; tb += 64) {
    const int nt = min(64, end - tb);
    // ---- phase 1: lane-parallel attention (once per edge), stage to LDS ----
    if (lane < nt) {
      int s = ssrc[tb + lane];          // coalesced
      float e = as[s] + ad;
      e = e > 0.f ? e : NEG_SLOPE * e;
      float pe = __expf(e);
      SlL += pe;
      s_s[wave][lane] = s;
      s_p[wave][lane] = pe;
    }
    // same-wave ds_write -> ds_read: in-order LDS, no barrier needed
    // ---- phase 2: feature accumulation, half-wave split ----
    int k = half;
    for (; k + 6 < nt; k += 8) {
      int s0 = s_s[wave][k];
      int s1 = s_s[wave][k + 2];
      int s2 = s_s[wave][k + 4];
      int s3 = s_s[wave][k + 6];
      float p0 = s_p[wave][k];
      float p1 = s_p[wave][k + 2];
      float p2 = s_p[wave][k + 4];
      float p3 = s_p[wave][k + 6];
      float2 f0 = __half22float2(*(const __half2*)(hsrc + (size_t)s0 * 64 + 2 * hl));
      float2 f1 = __half22float2(*(const __half2*)(hsrc + (size_t)s1 * 64 + 2 * hl));
      float2 f2 = __half22float2(*(const __half2*)(hsrc + (size_t)s2 * 64 + 2 * hl));
      float2 f3 = __half22float2(*(const __half2*)(hsrc + (size_t)s3 * 64 + 2 * hl));
      acc0A = fmaf(p0, f0.x, acc0A); acc1A = fmaf(p0, f0.y, acc1A);
      acc0B = fmaf(p1, f1.x, acc0B); acc1B = fmaf(p1, f1.y, acc1B);
      acc0A = fmaf(p2, f2.x, acc0A); acc1A = fmaf(p2, f2.y, acc1A);
      acc0B = fmaf(p3, f3.x, acc0B); acc1B = fmaf(p3, f3.y, acc1B);
    }
    for (; k < nt; k += 2) {
      int s0 = s_s[wave][k];
      float p0 = s_p[wave][k];
      float2 f0 = __half22float2(*(const __half2*)(hsrc + (size_t)s0 * 64 + 2 * hl));
      acc0A = fmaf(p0, f0.x, acc0A); acc1A = fmaf(p0, f0.y, acc1A);
    }
  }
  float acc0 = acc0A + acc0B, acc1 = acc1A + acc1B;
  acc0 += __shfl_xor(acc0, 32, 64);
  acc1 += __shfl_xor(acc1, 32, 64);
  float Sl = SlL;
#pragma unroll
  for (int off = 32; off > 0; off >>= 1) Sl += __shfl_xor(Sl, off, 64);
  const float inv = 1.f / (Sl + GAT_EPS);

  if (LAYER == 1) {
    float2 bb = ((const float2*)b1)[hl];
    float r0 = fmaxf(fmaf(acc0, inv, bb.x), 0.f);
    float r1 = fmaxf(fmaf(acc1, inv, bb.y), 0.f);
    if (half == 0)
      *(__half2*)(rl1 + (size_t)node * 64 + 2 * hl) = __floats2half2_rn(r0, r1);
    float2 was = ((const float2*)w2as)[hl];
    float2 wad = ((const float2*)w2ad)[hl];
    float va = fmaf(r0, was.x, r1 * was.y);
    float vd = fmaf(r0, wad.x, r1 * wad.y);
#pragma unroll
    for (int off = 16; off > 0; off >>= 1) {
      va += __shfl_xor(va, off, 64);
      vd += __shfl_xor(vd, off, 64);
    }
    if (lane == 0) { as2[node] = va; ad2[node] = vd; }
  } else {
    if (half == 0) {
      float2 o; o.x = acc0 * inv; o.y = acc1 * inv;
      *(float2*)(agg2 + (size_t)node * 64 + 2 * hl) = o;
    }
  }
}

// ---- final GEMM: out = agg2 @ W2 + b2 (64 -> 128) ----
__global__ __launch_bounds__(256) void gemm_out_kernel(
    const float* __restrict__ agg2, const float* __restrict__ W2,
    const float* __restrict__ b2, float* __restrict__ out, int N) {
  __shared__ float Wl[64 * 128];    // 32 KB, loaded once
  __shared__ float xsh[4][4][64];   // 4 KB: per-wave staging
  const int t = threadIdx.x;
  {
    const float4* Wv = (const float4*)W2;
    float4* Wd = (float4*)Wl;
    for (int i = t; i < 64 * 128 / 4; i += 256) Wd[i] = Wv[i];
  }
  __syncthreads();
  const int lane = t & 63;
  const int wave = t >> 6;
  const int wid = blockIdx.x * 4 + wave;
  const int npairs = gridDim.x * 2;          // wave pairs
  const int pair = wid >> 1;
  const int col = (wid & 1) * 64 + lane;     // 0..127
  const float bc = b2[col];
  for (int row4 = pair * 4; row4 < N; row4 += npairs * 4) {
    const int r0 = row4;
    const int r1 = min(row4 + 1, N - 1);
    const int r2 = min(row4 + 2, N - 1);
    const int r3 = min(row4 + 3, N - 1);
    xsh[wave][0][lane] = agg2[(size_t)r0 * 64 + lane];
    xsh[wave][1][lane] = agg2[(size_t)r1 * 64 + lane];
    xsh[wave][2][lane] = agg2[(size_t)r2 * 64 + lane];
    xsh[wave][3][lane] = agg2[(size_t)r3 * 64 + lane];
    float a0 = bc, a1 = bc, a2 = bc, a3 = bc;
#pragma unroll 4
    for (int kq = 0; kq < 64; kq += 4) {
      float4 x0 = *(const float4*)&xsh[wave][0][kq];  // uniform -> broadcast
      float4 x1 = *(const float4*)&xsh[wave][1][kq];
      float4 x2 = *(const float4*)&xsh[wave][2][kq];
      float4 x3 = *(const float4*)&xsh[wave][3][kq];
      float w0 = Wl[(kq + 0) * 128 + col];
      float w1 = Wl[(kq + 1) * 128 + col];
      float w2 = Wl[(kq + 2) * 128 + col];
      float w3 = Wl[(kq + 3) * 128 + col];
      a0 = fmaf(x0.x, w0, a0); a0 = fmaf(x0.y, w1, a0);
      a0 = fmaf(x0.z, w2, a0); a0 = fmaf(x0.w, w3, a0);
      a1 = fmaf(x1.x, w0, a1); a1 = fmaf(x1.y, w1, a1);
      a1 = fmaf(x1.z, w2, a1); a1 = fmaf(x1.w, w3, a1);
      a2 = fmaf(x2.x, w0, a2); a2 = fmaf(x2.y, w1, a2);
      a2 = fmaf(x2.z, w2, a2); a2 = fmaf(x2.w, w3, a2);
      a3 = fmaf(x3.x, w0, a3); a3 = fmaf(x3.y, w1, a3);
      a3 = fmaf(x3.z, w2, a3); a3 = fmaf(x3.w, w3, a3);
    }
    if (r0 < N) out[(size_t)r0 * 128 + col] = a0;
    if (row4 + 1 < N) out[(size_t)r1 * 128 + col] = a1;
    if (row4 + 2 < N) out[(size_t)r2 * 128 + col] = a2;
    if (row4 + 3 < N) out[(size_t)r3 * 128 + col] = a3;
  }
}

extern "C" void kernel_launch(void* const* d_in, const int* in_sizes, int n_in,
                              void* d_out, int out_size, void* d_ws, size_t ws_size,
                              hipStream_t stream) {
  const float* x    = (const float*)d_in[0];
  const int*   ei   = (const int*)d_in[1];
  const float* W1   = (const float*)d_in[2];
  const float* a_s1 = (const float*)d_in[3];
  const float* a_d1 = (const float*)d_in[4];
  const float* b1   = (const float*)d_in[5];
  const float* W2   = (const float*)d_in[6];
  const float* a_s2 = (const float*)d_in[7];
  const float* a_d2 = (const float*)d_in[8];
  const float* b2   = (const float*)d_in[9];

  const int N  = in_sizes[0] / 128;   // 50000
  const int E  = in_sizes[1] / 2;     // 1200000
  const int ET = E + N;               // 1250000
  const int* srcs = ei;
  const int* dsts = ei + E;
  const int nblk = (N + 255) / 256;
  const int NW = N / 2;                           // 25000 packed counter words
  const int HB = (ET + CHUNK - 1) >> CHUNK_LOG;   // 77 histogram blocks

  // workspace layout
  char* w = (char*)d_ws;
  __half* h16  = (__half*)w;            w += (size_t)N * 64 * 2;
  __half* rl1  = (__half*)w;            w += (size_t)N * 64 * 2;
  float* agg2  = (float*)w;             w += (size_t)N * 64 * 4;  // 12.8 MB
  float* as1   = (float*)w;             w += (size_t)N * 4;
  float* ad1   = (float*)w;             w += (size_t)N * 4;
  float* as2   = (float*)w;             w += (size_t)N * 4;
  float* ad2   = (float*)w;             w += (size_t)N * 4;
  float* w2as  = (float*)w;             w += 64 * 4;
  float* w2ad  = (float*)w;             w += 64 * 4;
  int* row_ptr = (int*)w;               w += (size_t)(N + 1) * 4;
  int* count   = (int*)w;               w += (size_t)N * 4;
  unsigned short* rank = (unsigned short*)w;  w += (size_t)ET * 2;
  int* ssrc    = (int*)w;               w += (size_t)ET * 4;
  int* bsums   = (int*)w;               w += (size_t)nblk * 4;
  // hist_g aliases agg2: lifetimes disjoint (CSR build vs layer-2 output).
  unsigned* hist_g = (unsigned*)agg2;

  float* out = (float*)d_out;  // N*128

  // ---- build CSR + sorted src permutation (zero global atomics) ----
  hist_local_kernel<<<HB, 256, 0, stream>>>(dsts, E, ET, hist_g, rank);
  col_scan_kernel<<<(NW + 255) / 256, 256, 0, stream>>>(hist_g, count, NW, HB);
  scan_blocks_kernel<<<nblk, 256, 0, stream>>>(count, row_ptr, bsums, N);
  scan_top_kernel<<<1, 256, 0, stream>>>(bsums, nblk);
  scan_add_kernel<<<nblk, 256, 0, stream>>>(row_ptr, bsums, N, ET);
  scatter2_kernel<<<2048, 256, 0, stream>>>(srcs, dsts, row_ptr, hist_g, rank,
                                            E, ET, ssrc);

  // ---- weights prep + layer-1 features ----
  prep_kernel<<<1, 128, 0, stream>>>(W2, a_s2, a_d2, w2as, w2ad);
  gemm1_kernel<<<1024, 256, 0, stream>>>(x, W1, a_s1, a_d1, h16, as1, ad1, N);
  // ---- layer-1 aggregation (phase-split attention, LDS staging) ----
  node_agg_kernel<1><<<(N + 3) / 4, 256, 0, stream>>>(
      row_ptr, ssrc, as1, ad1, h16, b1, w2as, w2ad, rl1, as2, ad2,
      (float*)nullptr, N);
  // ---- layer-2 aggregation (64-dim, W2 commuted out) ----
  node_agg_kernel<2><<<(N + 3) / 4, 256, 0, stream>>>(
      row_ptr, ssrc, as2, ad2, rl1, b1, w2as, w2ad, ((__half*)nullptr),
      (float*)nullptr, (float*)nullptr, agg2, N);
  // ---- final GEMM ----
  gemm_out_kernel<<<1024, 256, 0, stream>>>(agg2, W2, b2, out, N);
}

// Round 16
// 178.838 us; speedup vs baseline: 1.4795x; 1.1003x over previous
//
#include <hip/hip_runtime.h>
#include <hip/hip_fp16.h>

#define NEG_SLOPE 0.2f
#define GAT_EPS 1e-16f
#define CHUNK_LOG 14
#define CHUNK (1 << CHUNK_LOG)   // edges per histogram block
#define NWMAX 25088              // LDS u32 words (>= N/2 = 25000)

// ---- prep: w2as = W2 @ a_src2, w2ad = W2 @ a_dst2 (W2 is [64,128] row-major) ----
__global__ __launch_bounds__(128) void prep_kernel(
    const float* __restrict__ W2, const float* __restrict__ a_s2,
    const float* __restrict__ a_d2, float* __restrict__ w2as,
    float* __restrict__ w2ad) {
  const int t = threadIdx.x;  // 128 threads
  const int c = t & 63;
  const float* av = (t < 64) ? a_s2 : a_d2;
  float s = 0.f;
  for (int j = 0; j < 128; ++j) s = fmaf(W2[c * 128 + j], av[j], s);
  if (t < 64) w2as[c] = s; else w2ad[c] = s;
}

// ---- GEMM1: h1 = x @ W1 (128 -> 64) as fp16 + alpha reductions ----
__global__ __launch_bounds__(256) void gemm1_kernel(
    const float* __restrict__ x, const float* __restrict__ W1,
    const float* __restrict__ a_src, const float* __restrict__ a_dst,
    __half* __restrict__ h16, float* __restrict__ as_out,
    float* __restrict__ ad_out, int N) {
  __shared__ float Wl[128 * 64];      // 32 KB, loaded once
  __shared__ float xsh[4][4][128];    // 8 KB: per-wave staging (wave, row, k)
  const int t = threadIdx.x;
  {
    const float4* Wv = (const float4*)W1;
    float4* Wd = (float4*)Wl;
    for (int i = t; i < 128 * 64 / 4; i += 256) Wd[i] = Wv[i];
  }
  __syncthreads();
  const int lane = t & 63;
  const int wave = t >> 6;
  const int wid = blockIdx.x * 4 + wave;
  const int nwaves = gridDim.x * 4;
  const float asl = a_src[lane], adl = a_dst[lane];
  for (int row4 = wid * 4; row4 < N; row4 += nwaves * 4) {
    const int r0 = row4;
    const int r1 = min(row4 + 1, N - 1);
    const int r2 = min(row4 + 2, N - 1);
    const int r3 = min(row4 + 3, N - 1);
    float2 v0 = *(const float2*)(x + (size_t)r0 * 128 + lane * 2);
    float2 v1 = *(const float2*)(x + (size_t)r1 * 128 + lane * 2);
    float2 v2 = *(const float2*)(x + (size_t)r2 * 128 + lane * 2);
    float2 v3 = *(const float2*)(x + (size_t)r3 * 128 + lane * 2);
    *(float2*)&xsh[wave][0][lane * 2] = v0;
    *(float2*)&xsh[wave][1][lane * 2] = v1;
    *(float2*)&xsh[wave][2][lane * 2] = v2;
    *(float2*)&xsh[wave][3][lane * 2] = v3;
    float a0 = 0.f, a1 = 0.f, a2 = 0.f, a3 = 0.f;
#pragma unroll 4
    for (int kq = 0; kq < 128; kq += 4) {
      float4 x0 = *(const float4*)&xsh[wave][0][kq];  // uniform -> broadcast
      float4 x1 = *(const float4*)&xsh[wave][1][kq];
      float4 x2 = *(const float4*)&xsh[wave][2][kq];
      float4 x3 = *(const float4*)&xsh[wave][3][kq];
      float w0 = Wl[(kq + 0) * 64 + lane];
      float w1 = Wl[(kq + 1) * 64 + lane];
      float w2 = Wl[(kq + 2) * 64 + lane];
      float w3 = Wl[(kq + 3) * 64 + lane];
      a0 = fmaf(x0.x, w0, a0); a0 = fmaf(x0.y, w1, a0);
      a0 = fmaf(x0.z, w2, a0); a0 = fmaf(x0.w, w3, a0);
      a1 = fmaf(x1.x, w0, a1); a1 = fmaf(x1.y, w1, a1);
      a1 = fmaf(x1.z, w2, a1); a1 = fmaf(x1.w, w3, a1);
      a2 = fmaf(x2.x, w0, a2); a2 = fmaf(x2.y, w1, a2);
      a2 = fmaf(x2.z, w2, a2); a2 = fmaf(x2.w, w3, a2);
      a3 = fmaf(x3.x, w0, a3); a3 = fmaf(x3.y, w1, a3);
      a3 = fmaf(x3.z, w2, a3); a3 = fmaf(x3.w, w3, a3);
    }
    float acc[4] = {a0, a1, a2, a3};
#pragma unroll
    for (int r = 0; r < 4; ++r) {
      const int row = row4 + r;
      if (row >= N) break;
      h16[(size_t)row * 64 + lane] = __float2half(acc[r]);
      float va = acc[r] * asl;
      float vd = acc[r] * adl;
#pragma unroll
      for (int off = 32; off > 0; off >>= 1) {
        va += __shfl_down(va, off, 64);
        vd += __shfl_down(vd, off, 64);
      }
      if (lane == 0) { as_out[row] = va; ad_out[row] = vd; }
    }
  }
}

// ---- Pass A: per-block LDS histogram (u16 pairs) + local rank, 512 threads ----
__global__ __launch_bounds__(512) void hist_local_kernel(
    const int* __restrict__ dsts, int E, int ET,
    unsigned* __restrict__ hist_g, unsigned short* __restrict__ rank) {
  __shared__ unsigned h[NWMAX];  // ~100 KB: N/2 packed u16 counter pairs
  const int t = threadIdx.x;
  for (int w = t; w < NWMAX; w += 512) h[w] = 0u;
  __syncthreads();
  const int b = blockIdx.x;
  const int beg = b << CHUNK_LOG;
  const int end = min(beg + CHUNK, ET);
  for (int i = beg + t; i < end; i += 512) {
    int d = (i < E) ? dsts[i] : i - E;
    unsigned sh = (unsigned)(d & 1) * 16u;
    unsigned old = atomicAdd(&h[d >> 1], 1u << sh);
    rank[i] = (unsigned short)((old >> sh) & 0xffffu);
  }
  __syncthreads();
  unsigned* hg = hist_g + (size_t)b * (NWMAX);
  for (int w = t; w < NWMAX; w += 512) hg[w] = h[w];
}

// ---- Pass B: per-node exclusive prefix over blocks (in place) + totals ----
__global__ __launch_bounds__(256) void col_scan_kernel(
    unsigned* __restrict__ hist_g, int* __restrict__ count, int NW, int HB) {
  const int w = blockIdx.x * 256 + threadIdx.x;
  if (w >= NW) return;
  unsigned s0 = 0, s1 = 0;
#pragma unroll 4
  for (int b = 0; b < HB; ++b) {
    unsigned* p = hist_g + (size_t)b * (NWMAX) + w;
    unsigned v = *p;
    *p = s0 | (s1 << 16);
    s0 += v & 0xffffu;
    s1 += v >> 16;
  }
  ((int2*)count)[w] = make_int2((int)s0, (int)s1);
}

// ---- 3-stage exclusive scan over count[N] -> row_ptr[N+1] ----
__global__ __launch_bounds__(256) void scan_blocks_kernel(
    const int* __restrict__ count, int* __restrict__ row_ptr,
    int* __restrict__ bsums, int N) {
  __shared__ int sd[256];
  const int t = threadIdx.x;
  const int i = blockIdx.x * 256 + t;
  int v = (i < N) ? count[i] : 0;
  sd[t] = v;
  __syncthreads();
  for (int off = 1; off < 256; off <<= 1) {
    int add = (t >= off) ? sd[t - off] : 0;
    __syncthreads();
    sd[t] += add;
    __syncthreads();
  }
  if (i < N) row_ptr[i] = sd[t] - v;  // exclusive, partial
  if (t == 255) bsums[blockIdx.x] = sd[255];
}

__global__ __launch_bounds__(256) void scan_top_kernel(int* __restrict__ bsums,
                                                       int nblk) {
  __shared__ int sd[256];
  const int t = threadIdx.x;
  int v = (t < nblk) ? bsums[t] : 0;
  sd[t] = v;
  __syncthreads();
  for (int off = 1; off < 256; off <<= 1) {
    int add = (t >= off) ? sd[t - off] : 0;
    __syncthreads();
    sd[t] += add;
    __syncthreads();
  }
  if (t < nblk) bsums[t] = sd[t] - v;  // exclusive
}

__global__ __launch_bounds__(256) void scan_add_kernel(
    int* __restrict__ row_ptr, const int* __restrict__ bsums, int N, int ET) {
  const int i = blockIdx.x * 256 + threadIdx.x;
  if (i < N) row_ptr[i] += bsums[blockIdx.x];
  if (i == 0) row_ptr[N] = ET;
}

// ---- Pass C: atomic-free scatter, 4-edge packs (8 gathers in flight) ----
__global__ __launch_bounds__(256) void scatter2_kernel(
    const int* __restrict__ srcs, const int* __restrict__ dsts,
    const int* __restrict__ row_ptr, const unsigned* __restrict__ hist_g,
    const unsigned short* __restrict__ rank, int E, int ET,
    int* __restrict__ ssrc) {
  const int np = ET >> 2;
  for (int p = blockIdx.x * blockDim.x + threadIdx.x; p < np;
       p += gridDim.x * blockDim.x) {
    const int base = p * 4;
    int4 s4, d4;
    if (base + 3 < E) {
      s4 = *(const int4*)(srcs + base);
      d4 = *(const int4*)(dsts + base);
    } else {
      s4.x = d4.x = base + 0 - E;
      s4.y = d4.y = base + 1 - E;
      s4.z = d4.z = base + 2 - E;
      s4.w = d4.w = base + 3 - E;
      if (base + 0 < E) { s4.x = srcs[base + 0]; d4.x = dsts[base + 0]; }
      if (base + 1 < E) { s4.y = srcs[base + 1]; d4.y = dsts[base + 1]; }
      if (base + 2 < E) { s4.z = srcs[base + 2]; d4.z = dsts[base + 2]; }
      if (base + 3 < E) { s4.w = srcs[base + 3]; d4.w = dsts[base + 3]; }
    }
    ushort4 r4 = *(const ushort4*)(rank + base);
    // 4-pack never straddles a chunk boundary (CHUNK % 4 == 0)
    const unsigned* hg = hist_g + ((size_t)(base >> CHUNK_LOG)) * (NWMAX);
    int rp0 = row_ptr[d4.x], rp1 = row_ptr[d4.y];
    int rp2 = row_ptr[d4.z], rp3 = row_ptr[d4.w];
    unsigned h0 = hg[d4.x >> 1], h1 = hg[d4.y >> 1];
    unsigned h2 = hg[d4.z >> 1], h3 = hg[d4.w >> 1];
    int o0 = (int)((h0 >> ((unsigned)(d4.x & 1) * 16u)) & 0xffffu);
    int o1 = (int)((h1 >> ((unsigned)(d4.y & 1) * 16u)) & 0xffffu);
    int o2 = (int)((h2 >> ((unsigned)(d4.z & 1) * 16u)) & 0xffffu);
    int o3 = (int)((h3 >> ((unsigned)(d4.w & 1) * 16u)) & 0xffffu);
    ssrc[rp0 + o0 + (int)r4.x] = s4.x;
    ssrc[rp1 + o1 + (int)r4.y] = s4.y;
    ssrc[rp2 + o2 + (int)r4.z] = s4.z;
    ssrc[rp3 + o3 + (int)r4.w] = s4.w;
  }
  // scalar tail (ET % 4)
  if (blockIdx.x == 0 && threadIdx.x < (ET & 3)) {
    int i = (np << 2) + threadIdx.x;
    int s = (i < E) ? srcs[i] : i - E;
    int d = (i < E) ? dsts[i] : i - E;
    const unsigned* hg = hist_g + ((size_t)(i >> CHUNK_LOG)) * (NWMAX);
    int off = (int)((hg[d >> 1] >> ((unsigned)(d & 1) * 16u)) & 0xffffu);
    ssrc[row_ptr[d] + off + (int)rank[i]] = s;
  }
}

// ---- fused per-node aggregation: ONE NODE PER 32-LANE HALF (2 nodes/wave).
// Phase 1: lane-parallel pe over a 32-edge tile (coalesced ssrc), staged to
// per-half LDS slot. Phase 2: all 32 lanes of the half process each edge
// (broadcast LDS read of (s,pe), 128B contiguous half2 gather), 4x unroll.
// Accumulators are complete per lane (no cross-half combine); Sl/va/vd
// reduce within the 32-group (xor offsets 16..1 stay inside the half).
template <int LAYER>
__global__ __launch_bounds__(256) void node_agg_kernel(
    const int* __restrict__ row_ptr, const int* __restrict__ ssrc,
    const float* __restrict__ as, const float* __restrict__ ad_arr,
    const __half* __restrict__ hsrc, const float* __restrict__ b1,
    const float* __restrict__ w2as, const float* __restrict__ w2ad,
    __half* __restrict__ rl1, float* __restrict__ as2,
    float* __restrict__ ad2, float* __restrict__ agg2, int N) {
  __shared__ int   s_s[4][2][32];   // per-wave, per-half staged src ids
  __shared__ float s_p[4][2][32];   // per-wave, per-half staged edge weights
  const int lane = threadIdx.x & 63;
  const int wave = threadIdx.x >> 6;
  const int h32 = lane >> 5;        // which half-wave (= which node)
  const int l32 = lane & 31;        // lane within half / feature pair index
  const int node = blockIdx.x * 8 + wave * 2 + h32;
  if (node >= N) return;
  const int beg = row_ptr[node], end = row_ptr[node + 1];
  const float ad = ad_arr[node];

  float accA0 = 0.f, accA1 = 0.f, accB0 = 0.f, accB1 = 0.f;
  float SlL = 0.f;  // per-lane exp-sum (phase 1)
  for (int tb = beg; tb < end; tb += 32) {
    const int nt = min(32, end - tb);
    // ---- phase 1: lane-parallel attention (once per edge), stage to LDS ----
    if (l32 < nt) {
      int s = ssrc[tb + l32];           // coalesced
      float e = as[s] + ad;
      e = e > 0.f ? e : NEG_SLOPE * e;
      float pe = __expf(e);
      SlL += pe;
      s_s[wave][h32][l32] = s;
      s_p[wave][h32][l32] = pe;
    }
    // same-wave ds_write -> ds_read: in-order LDS, no barrier needed
    // ---- phase 2: all 32 lanes per edge, 4 gathers in flight per half ----
    int k = 0;
    for (; k + 3 < nt; k += 4) {
      int s0 = s_s[wave][h32][k];
      int s1 = s_s[wave][h32][k + 1];
      int s2 = s_s[wave][h32][k + 2];
      int s3 = s_s[wave][h32][k + 3];
      float p0 = s_p[wave][h32][k];
      float p1 = s_p[wave][h32][k + 1];
      float p2 = s_p[wave][h32][k + 2];
      float p3 = s_p[wave][h32][k + 3];
      float2 f0 = __half22float2(*(const __half2*)(hsrc + (size_t)s0 * 64 + 2 * l32));
      float2 f1 = __half22float2(*(const __half2*)(hsrc + (size_t)s1 * 64 + 2 * l32));
      float2 f2 = __half22float2(*(const __half2*)(hsrc + (size_t)s2 * 64 + 2 * l32));
      float2 f3 = __half22float2(*(const __half2*)(hsrc + (size_t)s3 * 64 + 2 * l32));
      accA0 = fmaf(p0, f0.x, accA0); accA1 = fmaf(p0, f0.y, accA1);
      accB0 = fmaf(p1, f1.x, accB0); accB1 = fmaf(p1, f1.y, accB1);
      accA0 = fmaf(p2, f2.x, accA0); accA1 = fmaf(p2, f2.y, accA1);
      accB0 = fmaf(p3, f3.x, accB0); accB1 = fmaf(p3, f3.y, accB1);
    }
    for (; k < nt; ++k) {
      int s0 = s_s[wave][h32][k];
      float p0 = s_p[wave][h32][k];
      float2 f0 = __half22float2(*(const __half2*)(hsrc + (size_t)s0 * 64 + 2 * l32));
      accA0 = fmaf(p0, f0.x, accA0); accA1 = fmaf(p0, f0.y, accA1);
    }
  }
  float acc0 = accA0 + accB0, acc1 = accA1 + accB1;  // complete per lane
  float Sl = SlL;
#pragma unroll
  for (int off = 16; off > 0; off >>= 1) Sl += __shfl_xor(Sl, off, 64);
  const float inv = 1.f / (Sl + GAT_EPS);

  if (LAYER == 1) {
    float2 bb = ((const float2*)b1)[l32];
    float r0 = fmaxf(fmaf(acc0, inv, bb.x), 0.f);
    float r1 = fmaxf(fmaf(acc1, inv, bb.y), 0.f);
    *(__half2*)(rl1 + (size_t)node * 64 + 2 * l32) = __floats2half2_rn(r0, r1);
    float2 was = ((const float2*)w2as)[l32];
    float2 wad = ((const float2*)w2ad)[l32];
    float va = fmaf(r0, was.x, r1 * was.y);
    float vd = fmaf(r0, wad.x, r1 * wad.y);
#pragma unroll
    for (int off = 16; off > 0; off >>= 1) {
      va += __shfl_xor(va, off, 64);
      vd += __shfl_xor(vd, off, 64);
    }
    if (l32 == 0) { as2[node] = va; ad2[node] = vd; }
  } else {
    float2 o; o.x = acc0 * inv; o.y = acc1 * inv;
    *(float2*)(agg2 + (size_t)node * 64 + 2 * l32) = o;
  }
}

// ---- final GEMM: out = agg2 @ W2 + b2 (64 -> 128) ----
__global__ __launch_bounds__(256) void gemm_out_kernel(
    const float* __restrict__ agg2, const float* __restrict__ W2,
    const float* __restrict__ b2, float* __restrict__ out, int N) {
  __shared__ float Wl[64 * 128];    // 32 KB, loaded once
  __shared__ float xsh[4][4][64];   // 4 KB: per-wave staging
  const int t = threadIdx.x;
  {
    const float4* Wv = (const float4*)W2;
    float4* Wd = (float4*)Wl;
    for (int i = t; i < 64 * 128 / 4; i += 256) Wd[i] = Wv[i];
  }
  __syncthreads();
  const int lane = t & 63;
  const int wave = t >> 6;
  const int wid = blockIdx.x * 4 + wave;
  const int npairs = gridDim.x * 2;          // wave pairs
  const int pair = wid >> 1;
  const int col = (wid & 1) * 64 + lane;     // 0..127
  const float bc = b2[col];
  for (int row4 = pair * 4; row4 < N; row4 += npairs * 4) {
    const int r0 = row4;
    const int r1 = min(row4 + 1, N - 1);
    const int r2 = min(row4 + 2, N - 1);
    const int r3 = min(row4 + 3, N - 1);
    xsh[wave][0][lane] = agg2[(size_t)r0 * 64 + lane];
    xsh[wave][1][lane] = agg2[(size_t)r1 * 64 + lane];
    xsh[wave][2][lane] = agg2[(size_t)r2 * 64 + lane];
    xsh[wave][3][lane] = agg2[(size_t)r3 * 64 + lane];
    float a0 = bc, a1 = bc, a2 = bc, a3 = bc;
#pragma unroll 4
    for (int kq = 0; kq < 64; kq += 4) {
      float4 x0 = *(const float4*)&xsh[wave][0][kq];  // uniform -> broadcast
      float4 x1 = *(const float4*)&xsh[wave][1][kq];
      float4 x2 = *(const float4*)&xsh[wave][2][kq];
      float4 x3 = *(const float4*)&xsh[wave][3][kq];
      float w0 = Wl[(kq + 0) * 128 + col];
      float w1 = Wl[(kq + 1) * 128 + col];
      float w2 = Wl[(kq + 2) * 128 + col];
      float w3 = Wl[(kq + 3) * 128 + col];
      a0 = fmaf(x0.x, w0, a0); a0 = fmaf(x0.y, w1, a0);
      a0 = fmaf(x0.z, w2, a0); a0 = fmaf(x0.w, w3, a0);
      a1 = fmaf(x1.x, w0, a1); a1 = fmaf(x1.y, w1, a1);
      a1 = fmaf(x1.z, w2, a1); a1 = fmaf(x1.w, w3, a1);
      a2 = fmaf(x2.x, w0, a2); a2 = fmaf(x2.y, w1, a2);
      a2 = fmaf(x2.z, w2, a2); a2 = fmaf(x2.w, w3, a2);
      a3 = fmaf(x3.x, w0, a3); a3 = fmaf(x3.y, w1, a3);
      a3 = fmaf(x3.z, w2, a3); a3 = fmaf(x3.w, w3, a3);
    }
    if (r0 < N) out[(size_t)r0 * 128 + col] = a0;
    if (row4 + 1 < N) out[(size_t)r1 * 128 + col] = a1;
    if (row4 + 2 < N) out[(size_t)r2 * 128 + col] = a2;
    if (row4 + 3 < N) out[(size_t)r3 * 128 + col] = a3;
  }
}

extern "C" void kernel_launch(void* const* d_in, const int* in_sizes, int n_in,
                              void* d_out, int out_size, void* d_ws, size_t ws_size,
                              hipStream_t stream) {
  const float* x    = (const float*)d_in[0];
  const int*   ei   = (const int*)d_in[1];
  const float* W1   = (const float*)d_in[2];
  const float* a_s1 = (const float*)d_in[3];
  const float* a_d1 = (const float*)d_in[4];
  const float* b1   = (const float*)d_in[5];
  const float* W2   = (const float*)d_in[6];
  const float* a_s2 = (const float*)d_in[7];
  const float* a_d2 = (const float*)d_in[8];
  const float* b2   = (const float*)d_in[9];

  const int N  = in_sizes[0] / 128;   // 50000
  const int E  = in_sizes[1] / 2;     // 1200000
  const int ET = E + N;               // 1250000
  const int* srcs = ei;
  const int* dsts = ei + E;
  const int nblk = (N + 255) / 256;
  const int NW = N / 2;                           // 25000 packed counter words
  const int HB = (ET + CHUNK - 1) >> CHUNK_LOG;   // 77 histogram blocks

  // workspace layout
  char* w = (char*)d_ws;
  __half* h16  = (__half*)w;            w += (size_t)N * 64 * 2;
  __half* rl1  = (__half*)w;            w += (size_t)N * 64 * 2;
  float* agg2  = (float*)w;             w += (size_t)N * 64 * 4;  // 12.8 MB
  float* as1   = (float*)w;             w += (size_t)N * 4;
  float* ad1   = (float*)w;             w += (size_t)N * 4;
  float* as2   = (float*)w;             w += (size_t)N * 4;
  float* ad2   = (float*)w;             w += (size_t)N * 4;
  float* w2as  = (float*)w;             w += 64 * 4;
  float* w2ad  = (float*)w;             w += 64 * 4;
  int* row_ptr = (int*)w;               w += (size_t)(N + 1) * 4;
  int* count   = (int*)w;               w += (size_t)N * 4;
  unsigned short* rank = (unsigned short*)w;  w += (size_t)ET * 2;
  int* ssrc    = (int*)w;               w += (size_t)ET * 4;
  int* bsums   = (int*)w;               w += (size_t)nblk * 4;
  // hist_g aliases agg2: lifetimes disjoint (CSR build vs layer-2 output).
  unsigned* hist_g = (unsigned*)agg2;

  float* out = (float*)d_out;  // N*128

  // ---- build CSR + sorted src permutation (zero global atomics) ----
  hist_local_kernel<<<HB, 512, 0, stream>>>(dsts, E, ET, hist_g, rank);
  col_scan_kernel<<<(NW + 255) / 256, 256, 0, stream>>>(hist_g, count, NW, HB);
  scan_blocks_kernel<<<nblk, 256, 0, stream>>>(count, row_ptr, bsums, N);
  scan_top_kernel<<<1, 256, 0, stream>>>(bsums, nblk);
  scan_add_kernel<<<nblk, 256, 0, stream>>>(row_ptr, bsums, N, ET);
  scatter2_kernel<<<2048, 256, 0, stream>>>(srcs, dsts, row_ptr, hist_g, rank,
                                            E, ET, ssrc);

  // ---- weights prep + layer-1 features ----
  prep_kernel<<<1, 128, 0, stream>>>(W2, a_s2, a_d2, w2as, w2ad);
  gemm1_kernel<<<1024, 256, 0, stream>>>(x, W1, a_s1, a_d1, h16, as1, ad1, N);
  // ---- layer-1 aggregation (half-wave per node) ----
  node_agg_kernel<1><<<(N + 7) / 8, 256, 0, stream>>>(
      row_ptr, ssrc, as1, ad1, h16, b1, w2as, w2ad, rl1, as2, ad2,
      (float*)nullptr, N);
  // ---- layer-2 aggregation (64-dim, W2 commuted out) ----
  node_agg_kernel<2><<<(N + 7) / 8, 256, 0, stream>>>(
      row_ptr, ssrc, as2, ad2, rl1, b1, w2as, w2ad, ((__half*)nullptr),
      (float*)nullptr, (float*)nullptr, agg2, N);
  // ---- final GEMM ----
  gemm_out_kernel<<<1024, 256, 0, stream>>>(agg2, W2, b2, out, N);
}

// Round 17
// 177.814 us; speedup vs baseline: 1.4880x; 1.0058x over previous
//
#include <hip/hip_runtime.h>
#include <hip/hip_fp16.h>

#define NEG_SLOPE 0.2f
#define GAT_EPS 1e-16f
#define CHUNK_LOG 14
#define CHUNK (1 << CHUNK_LOG)   // edges per histogram block
#define NWMAX 25088              // LDS u32 words (>= N/2 = 25000)

// ---- prep: w2as = W2 @ a_src2, w2ad = W2 @ a_dst2 (W2 is [64,128] row-major) ----
__global__ __launch_bounds__(128) void prep_kernel(
    const float* __restrict__ W2, const float* __restrict__ a_s2,
    const float* __restrict__ a_d2, float* __restrict__ w2as,
    float* __restrict__ w2ad) {
  const int t = threadIdx.x;  // 128 threads
  const int c = t & 63;
  const float* av = (t < 64) ? a_s2 : a_d2;
  float s = 0.f;
  for (int j = 0; j < 128; ++j) s = fmaf(W2[c * 128 + j], av[j], s);
  if (t < 64) w2as[c] = s; else w2ad[c] = s;
}

// ---- GEMM1: h1 = x @ W1 (128 -> 64) as fp16 + alpha reductions ----
__global__ __launch_bounds__(256) void gemm1_kernel(
    const float* __restrict__ x, const float* __restrict__ W1,
    const float* __restrict__ a_src, const float* __restrict__ a_dst,
    __half* __restrict__ h16, float* __restrict__ as_out,
    float* __restrict__ ad_out, int N) {
  __shared__ float Wl[128 * 64];      // 32 KB, loaded once
  __shared__ float xsh[4][4][128];    // 8 KB: per-wave staging (wave, row, k)
  const int t = threadIdx.x;
  {
    const float4* Wv = (const float4*)W1;
    float4* Wd = (float4*)Wl;
    for (int i = t; i < 128 * 64 / 4; i += 256) Wd[i] = Wv[i];
  }
  __syncthreads();
  const int lane = t & 63;
  const int wave = t >> 6;
  const int wid = blockIdx.x * 4 + wave;
  const int nwaves = gridDim.x * 4;
  const float asl = a_src[lane], adl = a_dst[lane];
  for (int row4 = wid * 4; row4 < N; row4 += nwaves * 4) {
    const int r0 = row4;
    const int r1 = min(row4 + 1, N - 1);
    const int r2 = min(row4 + 2, N - 1);
    const int r3 = min(row4 + 3, N - 1);
    float2 v0 = *(const float2*)(x + (size_t)r0 * 128 + lane * 2);
    float2 v1 = *(const float2*)(x + (size_t)r1 * 128 + lane * 2);
    float2 v2 = *(const float2*)(x + (size_t)r2 * 128 + lane * 2);
    float2 v3 = *(const float2*)(x + (size_t)r3 * 128 + lane * 2);
    *(float2*)&xsh[wave][0][lane * 2] = v0;
    *(float2*)&xsh[wave][1][lane * 2] = v1;
    *(float2*)&xsh[wave][2][lane * 2] = v2;
    *(float2*)&xsh[wave][3][lane * 2] = v3;
    float a0 = 0.f, a1 = 0.f, a2 = 0.f, a3 = 0.f;
#pragma unroll 4
    for (int kq = 0; kq < 128; kq += 4) {
      float4 x0 = *(const float4*)&xsh[wave][0][kq];  // uniform -> broadcast
      float4 x1 = *(const float4*)&xsh[wave][1][kq];
      float4 x2 = *(const float4*)&xsh[wave][2][kq];
      float4 x3 = *(const float4*)&xsh[wave][3][kq];
      float w0 = Wl[(kq + 0) * 64 + lane];
      float w1 = Wl[(kq + 1) * 64 + lane];
      float w2 = Wl[(kq + 2) * 64 + lane];
      float w3 = Wl[(kq + 3) * 64 + lane];
      a0 = fmaf(x0.x, w0, a0); a0 = fmaf(x0.y, w1, a0);
      a0 = fmaf(x0.z, w2, a0); a0 = fmaf(x0.w, w3, a0);
      a1 = fmaf(x1.x, w0, a1); a1 = fmaf(x1.y, w1, a1);
      a1 = fmaf(x1.z, w2, a1); a1 = fmaf(x1.w, w3, a1);
      a2 = fmaf(x2.x, w0, a2); a2 = fmaf(x2.y, w1, a2);
      a2 = fmaf(x2.z, w2, a2); a2 = fmaf(x2.w, w3, a2);
      a3 = fmaf(x3.x, w0, a3); a3 = fmaf(x3.y, w1, a3);
      a3 = fmaf(x3.z, w2, a3); a3 = fmaf(x3.w, w3, a3);
    }
    float acc[4] = {a0, a1, a2, a3};
#pragma unroll
    for (int r = 0; r < 4; ++r) {
      const int row = row4 + r;
      if (row >= N) break;
      h16[(size_t)row * 64 + lane] = __float2half(acc[r]);
      float va = acc[r] * asl;
      float vd = acc[r] * adl;
#pragma unroll
      for (int off = 32; off > 0; off >>= 1) {
        va += __shfl_down(va, off, 64);
        vd += __shfl_down(vd, off, 64);
      }
      if (lane == 0) { as_out[row] = va; ad_out[row] = vd; }
    }
  }
}

// ---- Pass A: per-block LDS histogram (u16 pairs) + local rank, 512 threads ----
__global__ __launch_bounds__(512) void hist_local_kernel(
    const int* __restrict__ dsts, int E, int ET,
    unsigned* __restrict__ hist_g, unsigned short* __restrict__ rank) {
  __shared__ unsigned h[NWMAX];  // ~100 KB: N/2 packed u16 counter pairs
  const int t = threadIdx.x;
  for (int w = t; w < NWMAX; w += 512) h[w] = 0u;
  __syncthreads();
  const int b = blockIdx.x;
  const int beg = b << CHUNK_LOG;
  const int end = min(beg + CHUNK, ET);
  for (int i = beg + t; i < end; i += 512) {
    int d = (i < E) ? dsts[i] : i - E;
    unsigned sh = (unsigned)(d & 1) * 16u;
    unsigned old = atomicAdd(&h[d >> 1], 1u << sh);
    rank[i] = (unsigned short)((old >> sh) & 0xffffu);
  }
  __syncthreads();
  unsigned* hg = hist_g + (size_t)b * (NWMAX);
  for (int w = t; w < NWMAX; w += 512) hg[w] = h[w];
}

// ---- Pass B: per-node exclusive prefix over blocks (in place) + totals ----
__global__ __launch_bounds__(256) void col_scan_kernel(
    unsigned* __restrict__ hist_g, int* __restrict__ count, int NW, int HB) {
  const int w = blockIdx.x * 256 + threadIdx.x;
  if (w >= NW) return;
  unsigned s0 = 0, s1 = 0;
#pragma unroll 4
  for (int b = 0; b < HB; ++b) {
    unsigned* p = hist_g + (size_t)b * (NWMAX) + w;
    unsigned v = *p;
    *p = s0 | (s1 << 16);
    s0 += v & 0xffffu;
    s1 += v >> 16;
  }
  ((int2*)count)[w] = make_int2((int)s0, (int)s1);
}

// ---- 3-stage exclusive scan over count[N] -> row_ptr[N+1] ----
__global__ __launch_bounds__(256) void scan_blocks_kernel(
    const int* __restrict__ count, int* __restrict__ row_ptr,
    int* __restrict__ bsums, int N) {
  __shared__ int sd[256];
  const int t = threadIdx.x;
  const int i = blockIdx.x * 256 + t;
  int v = (i < N) ? count[i] : 0;
  sd[t] = v;
  __syncthreads();
  for (int off = 1; off < 256; off <<= 1) {
    int add = (t >= off) ? sd[t - off] : 0;
    __syncthreads();
    sd[t] += add;
    __syncthreads();
  }
  if (i < N) row_ptr[i] = sd[t] - v;  // exclusive, partial
  if (t == 255) bsums[blockIdx.x] = sd[255];
}

__global__ __launch_bounds__(256) void scan_top_kernel(int* __restrict__ bsums,
                                                       int nblk) {
  __shared__ int sd[256];
  const int t = threadIdx.x;
  int v = (t < nblk) ? bsums[t] : 0;
  sd[t] = v;
  __syncthreads();
  for (int off = 1; off < 256; off <<= 1) {
    int add = (t >= off) ? sd[t - off] : 0;
    __syncthreads();
    sd[t] += add;
    __syncthreads();
  }
  if (t < nblk) bsums[t] = sd[t] - v;  // exclusive
}

__global__ __launch_bounds__(256) void scan_add_kernel(
    int* __restrict__ row_ptr, const int* __restrict__ bsums, int N, int ET) {
  const int i = blockIdx.x * 256 + threadIdx.x;
  if (i < N) row_ptr[i] += bsums[blockIdx.x];
  if (i == 0) row_ptr[N] = ET;
}

// ---- Pass C: atomic-free scatter, 8-edge packs (8 gather chains/thread) ----
__global__ __launch_bounds__(256) void scatter2_kernel(
    const int* __restrict__ srcs, const int* __restrict__ dsts,
    const int* __restrict__ row_ptr, const unsigned* __restrict__ hist_g,
    const unsigned short* __restrict__ rank, int E, int ET,
    int* __restrict__ ssrc) {
  const int np = ET >> 3;
  for (int p = blockIdx.x * blockDim.x + threadIdx.x; p < np;
       p += gridDim.x * blockDim.x) {
    const int base = p * 8;
    int s[8], d[8];
    if (base + 7 < E) {
      *(int4*)&s[0] = *(const int4*)(srcs + base);
      *(int4*)&s[4] = *(const int4*)(srcs + base + 4);
      *(int4*)&d[0] = *(const int4*)(dsts + base);
      *(int4*)&d[4] = *(const int4*)(dsts + base + 4);
    } else {
#pragma unroll
      for (int j = 0; j < 8; ++j) {
        int i = base + j;
        s[j] = (i < E) ? srcs[i] : i - E;
        d[j] = (i < E) ? dsts[i] : i - E;
      }
    }
    unsigned short r[8];
    *(ushort4*)&r[0] = *(const ushort4*)(rank + base);
    *(ushort4*)&r[4] = *(const ushort4*)(rank + base + 4);
    // 8-pack never straddles a chunk boundary (CHUNK % 8 == 0)
    const unsigned* hg = hist_g + ((size_t)(base >> CHUNK_LOG)) * (NWMAX);
    int rp[8];
    unsigned hh[8];
#pragma unroll
    for (int j = 0; j < 8; ++j) rp[j] = row_ptr[d[j]];
#pragma unroll
    for (int j = 0; j < 8; ++j) hh[j] = hg[d[j] >> 1];
#pragma unroll
    for (int j = 0; j < 8; ++j) {
      int off = (int)((hh[j] >> ((unsigned)(d[j] & 1) * 16u)) & 0xffffu);
      ssrc[rp[j] + off + (int)r[j]] = s[j];
    }
  }
  // scalar tail (ET % 8)
  if (blockIdx.x == 0 && threadIdx.x < (ET & 7)) {
    int i = (np << 3) + threadIdx.x;
    int s = (i < E) ? srcs[i] : i - E;
    int d = (i < E) ? dsts[i] : i - E;
    const unsigned* hg = hist_g + ((size_t)(i >> CHUNK_LOG)) * (NWMAX);
    int off = (int)((hg[d >> 1] >> ((unsigned)(d & 1) * 16u)) & 0xffffu);
    ssrc[row_ptr[d] + off + (int)rank[i]] = s;
  }
}

// ---- fused per-node aggregation: one node per 32-lane half (2 nodes/wave).
// Phase 1: lane-parallel pe over a 32-edge tile, staged to per-half LDS.
// Phase 2: all 32 lanes per edge, 8 gathers in flight per half. ----
template <int LAYER>
__global__ __launch_bounds__(256) void node_agg_kernel(
    const int* __restrict__ row_ptr, const int* __restrict__ ssrc,
    const float* __restrict__ as, const float* __restrict__ ad_arr,
    const __half* __restrict__ hsrc, const float* __restrict__ b1,
    const float* __restrict__ w2as, const float* __restrict__ w2ad,
    __half* __restrict__ rl1, float* __restrict__ as2,
    float* __restrict__ ad2, float* __restrict__ agg2, int N) {
  __shared__ int   s_s[4][2][32];   // per-wave, per-half staged src ids
  __shared__ float s_p[4][2][32];   // per-wave, per-half staged edge weights
  const int lane = threadIdx.x & 63;
  const int wave = threadIdx.x >> 6;
  const int h32 = lane >> 5;        // which half-wave (= which node)
  const int l32 = lane & 31;        // lane within half / feature pair index
  const int node = blockIdx.x * 8 + wave * 2 + h32;
  if (node >= N) return;
  const int beg = row_ptr[node], end = row_ptr[node + 1];
  const float ad = ad_arr[node];

  float accA0 = 0.f, accA1 = 0.f, accB0 = 0.f, accB1 = 0.f;
  float SlL = 0.f;  // per-lane exp-sum (phase 1)
  for (int tb = beg; tb < end; tb += 32) {
    const int nt = min(32, end - tb);
    // ---- phase 1: lane-parallel attention (once per edge), stage to LDS ----
    if (l32 < nt) {
      int s = ssrc[tb + l32];           // coalesced
      float e = as[s] + ad;
      e = e > 0.f ? e : NEG_SLOPE * e;
      float pe = __expf(e);
      SlL += pe;
      s_s[wave][h32][l32] = s;
      s_p[wave][h32][l32] = pe;
    }
    // same-wave ds_write -> ds_read: in-order LDS, no barrier needed
    // ---- phase 2: all 32 lanes per edge, 8 gathers in flight per half ----
    int k = 0;
    for (; k + 7 < nt; k += 8) {
      int   sv[8];
      float pv[8];
      float2 fv[8];
#pragma unroll
      for (int j = 0; j < 8; ++j) {
        sv[j] = s_s[wave][h32][k + j];
        pv[j] = s_p[wave][h32][k + j];
      }
#pragma unroll
      for (int j = 0; j < 8; ++j)
        fv[j] = __half22float2(
            *(const __half2*)(hsrc + (size_t)sv[j] * 64 + 2 * l32));
#pragma unroll
      for (int j = 0; j < 8; j += 2) {
        accA0 = fmaf(pv[j], fv[j].x, accA0);
        accA1 = fmaf(pv[j], fv[j].y, accA1);
        accB0 = fmaf(pv[j + 1], fv[j + 1].x, accB0);
        accB1 = fmaf(pv[j + 1], fv[j + 1].y, accB1);
      }
    }
    for (; k + 3 < nt; k += 4) {
      int s0 = s_s[wave][h32][k];
      int s1 = s_s[wave][h32][k + 1];
      int s2 = s_s[wave][h32][k + 2];
      int s3 = s_s[wave][h32][k + 3];
      float p0 = s_p[wave][h32][k];
      float p1 = s_p[wave][h32][k + 1];
      float p2 = s_p[wave][h32][k + 2];
      float p3 = s_p[wave][h32][k + 3];
      float2 f0 = __half22float2(*(const __half2*)(hsrc + (size_t)s0 * 64 + 2 * l32));
      float2 f1 = __half22float2(*(const __half2*)(hsrc + (size_t)s1 * 64 + 2 * l32));
      float2 f2 = __half22float2(*(const __half2*)(hsrc + (size_t)s2 * 64 + 2 * l32));
      float2 f3 = __half22float2(*(const __half2*)(hsrc + (size_t)s3 * 64 + 2 * l32));
      accA0 = fmaf(p0, f0.x, accA0); accA1 = fmaf(p0, f0.y, accA1);
      accB0 = fmaf(p1, f1.x, accB0); accB1 = fmaf(p1, f1.y, accB1);
      accA0 = fmaf(p2, f2.x, accA0); accA1 = fmaf(p2, f2.y, accA1);
      accB0 = fmaf(p3, f3.x, accB0); accB1 = fmaf(p3, f3.y, accB1);
    }
    for (; k < nt; ++k) {
      int s0 = s_s[wave][h32][k];
      float p0 = s_p[wave][h32][k];
      float2 f0 = __half22float2(*(const __half2*)(hsrc + (size_t)s0 * 64 + 2 * l32));
      accA0 = fmaf(p0, f0.x, accA0); accA1 = fmaf(p0, f0.y, accA1);
    }
  }
  float acc0 = accA0 + accB0, acc1 = accA1 + accB1;  // complete per lane
  float Sl = SlL;
#pragma unroll
  for (int off = 16; off > 0; off >>= 1) Sl += __shfl_xor(Sl, off, 64);
  const float inv = 1.f / (Sl + GAT_EPS);

  if (LAYER == 1) {
    float2 bb = ((const float2*)b1)[l32];
    float r0 = fmaxf(fmaf(acc0, inv, bb.x), 0.f);
    float r1 = fmaxf(fmaf(acc1, inv, bb.y), 0.f);
    *(__half2*)(rl1 + (size_t)node * 64 + 2 * l32) = __floats2half2_rn(r0, r1);
    float2 was = ((const float2*)w2as)[l32];
    float2 wad = ((const float2*)w2ad)[l32];
    float va = fmaf(r0, was.x, r1 * was.y);
    float vd = fmaf(r0, wad.x, r1 * wad.y);
#pragma unroll
    for (int off = 16; off > 0; off >>= 1) {
      va += __shfl_xor(va, off, 64);
      vd += __shfl_xor(vd, off, 64);
    }
    if (l32 == 0) { as2[node] = va; ad2[node] = vd; }
  } else {
    float2 o; o.x = acc0 * inv; o.y = acc1 * inv;
    *(float2*)(agg2 + (size_t)node * 64 + 2 * l32) = o;
  }
}

// ---- final GEMM: out = agg2 @ W2 + b2 (64 -> 128) ----
__global__ __launch_bounds__(256) void gemm_out_kernel(
    const float* __restrict__ agg2, const float* __restrict__ W2,
    const float* __restrict__ b2, float* __restrict__ out, int N) {
  __shared__ float Wl[64 * 128];    // 32 KB, loaded once
  __shared__ float xsh[4][4][64];   // 4 KB: per-wave staging
  const int t = threadIdx.x;
  {
    const float4* Wv = (const float4*)W2;
    float4* Wd = (float4*)Wl;
    for (int i = t; i < 64 * 128 / 4; i += 256) Wd[i] = Wv[i];
  }
  __syncthreads();
  const int lane = t & 63;
  const int wave = t >> 6;
  const int wid = blockIdx.x * 4 + wave;
  const int npairs = gridDim.x * 2;          // wave pairs
  const int pair = wid >> 1;
  const int col = (wid & 1) * 64 + lane;     // 0..127
  const float bc = b2[col];
  for (int row4 = pair * 4; row4 < N; row4 += npairs * 4) {
    const int r0 = row4;
    const int r1 = min(row4 + 1, N - 1);
    const int r2 = min(row4 + 2, N - 1);
    const int r3 = min(row4 + 3, N - 1);
    xsh[wave][0][lane] = agg2[(size_t)r0 * 64 + lane];
    xsh[wave][1][lane] = agg2[(size_t)r1 * 64 + lane];
    xsh[wave][2][lane] = agg2[(size_t)r2 * 64 + lane];
    xsh[wave][3][lane] = agg2[(size_t)r3 * 64 + lane];
    float a0 = bc, a1 = bc, a2 = bc, a3 = bc;
#pragma unroll 4
    for (int kq = 0; kq < 64; kq += 4) {
      float4 x0 = *(const float4*)&xsh[wave][0][kq];  // uniform -> broadcast
      float4 x1 = *(const float4*)&xsh[wave][1][kq];
      float4 x2 = *(const float4*)&xsh[wave][2][kq];
      float4 x3 = *(const float4*)&xsh[wave][3][kq];
      float w0 = Wl[(kq + 0) * 128 + col];
      float w1 = Wl[(kq + 1) * 128 + col];
      float w2 = Wl[(kq + 2) * 128 + col];
      float w3 = Wl[(kq + 3) * 128 + col];
      a0 = fmaf(x0.x, w0, a0); a0 = fmaf(x0.y, w1, a0);
      a0 = fmaf(x0.z, w2, a0); a0 = fmaf(x0.w, w3, a0);
      a1 = fmaf(x1.x, w0, a1); a1 = fmaf(x1.y, w1, a1);
      a1 = fmaf(x1.z, w2, a1); a1 = fmaf(x1.w, w3, a1);
      a2 = fmaf(x2.x, w0, a2); a2 = fmaf(x2.y, w1, a2);
      a2 = fmaf(x2.z, w2, a2); a2 = fmaf(x2.w, w3, a2);
      a3 = fmaf(x3.x, w0, a3); a3 = fmaf(x3.y, w1, a3);
      a3 = fmaf(x3.z, w2, a3); a3 = fmaf(x3.w, w3, a3);
    }
    if (r0 < N) out[(size_t)r0 * 128 + col] = a0;
    if (row4 + 1 < N) out[(size_t)r1 * 128 + col] = a1;
    if (row4 + 2 < N) out[(size_t)r2 * 128 + col] = a2;
    if (row4 + 3 < N) out[(size_t)r3 * 128 + col] = a3;
  }
}

extern "C" void kernel_launch(void* const* d_in, const int* in_sizes, int n_in,
                              void* d_out, int out_size, void* d_ws, size_t ws_size,
                              hipStream_t stream) {
  const float* x    = (const float*)d_in[0];
  const int*   ei   = (const int*)d_in[1];
  const float* W1   = (const float*)d_in[2];
  const float* a_s1 = (const float*)d_in[3];
  const float* a_d1 = (const float*)d_in[4];
  const float* b1   = (const float*)d_in[5];
  const float* W2   = (const float*)d_in[6];
  const float* a_s2 = (const float*)d_in[7];
  const float* a_d2 = (const float*)d_in[8];
  const float* b2   = (const float*)d_in[9];

  const int N  = in_sizes[0] / 128;   // 50000
  const int E  = in_sizes[1] / 2;     // 1200000
  const int ET = E + N;               // 1250000
  const int* srcs = ei;
  const int* dsts = ei + E;
  const int nblk = (N + 255) / 256;
  const int NW = N / 2;                           // 25000 packed counter words
  const int HB = (ET + CHUNK - 1) >> CHUNK_LOG;   // 77 histogram blocks

  // workspace layout
  char* w = (char*)d_ws;
  __half* h16  = (__half*)w;            w += (size_t)N * 64 * 2;
  __half* rl1  = (__half*)w;            w += (size_t)N * 64 * 2;
  float* agg2  = (float*)w;             w += (size_t)N * 64 * 4;  // 12.8 MB
  float* as1   = (float*)w;             w += (size_t)N * 4;
  float* ad1   = (float*)w;             w += (size_t)N * 4;
  float* as2   = (float*)w;             w += (size_t)N * 4;
  float* ad2   = (float*)w;             w += (size_t)N * 4;
  float* w2as  = (float*)w;             w += 64 * 4;
  float* w2ad  = (float*)w;             w += 64 * 4;
  int* row_ptr = (int*)w;               w += (size_t)(N + 1) * 4;
  int* count   = (int*)w;               w += (size_t)N * 4;
  unsigned short* rank = (unsigned short*)w;  w += (size_t)ET * 2;
  int* ssrc    = (int*)w;               w += (size_t)ET * 4;
  int* bsums   = (int*)w;               w += (size_t)nblk * 4;
  // hist_g aliases agg2: lifetimes disjoint (CSR build vs layer-2 output).
  unsigned* hist_g = (unsigned*)agg2;

  float* out = (float*)d_out;  // N*128

  // ---- build CSR + sorted src permutation (zero global atomics) ----
  hist_local_kernel<<<HB, 512, 0, stream>>>(dsts, E, ET, hist_g, rank);
  col_scan_kernel<<<(NW + 255) / 256, 256, 0, stream>>>(hist_g, count, NW, HB);
  scan_blocks_kernel<<<nblk, 256, 0, stream>>>(count, row_ptr, bsums, N);
  scan_top_kernel<<<1, 256, 0, stream>>>(bsums, nblk);
  scan_add_kernel<<<nblk, 256, 0, stream>>>(row_ptr, bsums, N, ET);
  scatter2_kernel<<<640, 256, 0, stream>>>(srcs, dsts, row_ptr, hist_g, rank,
                                           E, ET, ssrc);

  // ---- weights prep + layer-1 features ----
  prep_kernel<<<1, 128, 0, stream>>>(W2, a_s2, a_d2, w2as, w2ad);
  gemm1_kernel<<<1024, 256, 0, stream>>>(x, W1, a_s1, a_d1, h16, as1, ad1, N);
  // ---- layer-1 aggregation (half-wave per node) ----
  node_agg_kernel<1><<<(N + 7) / 8, 256, 0, stream>>>(
      row_ptr, ssrc, as1, ad1, h16, b1, w2as, w2ad, rl1, as2, ad2,
      (float*)nullptr, N);
  // ---- layer-2 aggregation (64-dim, W2 commuted out) ----
  node_agg_kernel<2><<<(N + 7) / 8, 256, 0, stream>>>(
      row_ptr, ssrc, as2, ad2, rl1, b1, w2as, w2ad, ((__half*)nullptr),
      (float*)nullptr, (float*)nullptr, agg2, N);
  // ---- final GEMM ----
  gemm_out_kernel<<<1024, 256, 0, stream>>>(agg2, W2, b2, out, N);
}